// Round 10
// baseline (87.524 us; speedup 1.0000x reference)
//
#include <hip/hip_runtime.h>
#include <math.h>

#define H 2048
#define E 64
#define TAU 1e-6f     // p-gap guard (proven r3/5/6/7/8/9): logit err ~2.5e-7 -> p err ~4e-9 << TAU

// ---- MFMA path geometry ----
#define MT 16         // rows per block -> grid 1024
#define KCW 16        // kc per wave (K-quarter = 512 elems; kc = 32 k)

// ---- round-5 fallback geometry ----
#define RB 16
#define CB 512
#define NCH (H / CB)
#define PITCH 516

// d_ws layout
#define WHI_OFF 65792u                     // after flags (65540 B), 256-aligned
#define WFRAG_BYTES 262144u                // 64kc * 4n * 64lane * 8 bf16 * 2B
#define WLO_OFF (WHI_OFF + WFRAG_BYTES)
#define WS_NEEDED ((size_t)(WLO_OFF + WFRAG_BYTES))   // 590080

typedef __attribute__((ext_vector_type(8))) short short8;
typedef __attribute__((ext_vector_type(4))) float f32x4;

__device__ __forceinline__ unsigned short bf16_rne(float f) {
    unsigned u = __float_as_uint(f);
    unsigned r = u + 0x7fffu + ((u >> 16) & 1u);
    return (unsigned short)(r >> 16);
}

// ============ kernel P: W' = pds*W (f64), split into bf16 hi/lo B-fragments ============
// frag elem (kc,n,lane,j) = W'[kc*32 + (lane>>4)*8 + j][n*16 + (lane&15)]
// pds is FOLDED here so the router needs no per-element scale (x@(pds*W)).
__global__ __launch_bounds__(64)
void prep_w(const float* __restrict__ Wm, const float* __restrict__ pds,
            int* __restrict__ flags,
            unsigned short* __restrict__ whi, unsigned short* __restrict__ wlo)
{
    const int fb   = blockIdx.x;        // 0..255 = kc*4 + n
    const int lane = threadIdx.x;       // 0..63
    if (fb == 0 && lane == 0) flags[0] = 0;
    const int kc  = fb >> 2;
    const int n   = fb & 3;
    const int r0  = kc * 32 + (lane >> 4) * 8;
    const int col = n * 16 + (lane & 15);

    short8 hv, lv;
#pragma unroll
    for (int j = 0; j < 8; ++j) {
        const int r = r0 + j;
        const double w = (double)pds[r] * (double)Wm[r * E + col];  // exact in f64
        const unsigned short hb = bf16_rne((float)w);
        const double hd = (double)__uint_as_float((unsigned)hb << 16);
        const unsigned short lb = bf16_rne((float)(w - hd));
        hv[j] = (short)hb;
        lv[j] = (short)lb;
    }
    const size_t off = ((size_t)fb * 64 + lane) * 8;
    *(short8*)(whi + off) = hv;
    *(short8*)(wlo + off) = lv;
}

// ============ kernel M: direct-fragment MFMA router (no LDS in K-loop) ============
// Wave wid owns K-quarter [512*wid, +512) for the block's 16 rows. x is loaded
// DIRECTLY in A-fragment layout (row=lane&15, k=(lane>>4)*8+j -> 2 dwordx4/kc,
// lines fully consumed across lanes), converted in-register to bf16 hi/lo.
// No LDS staging, no barriers, minimal live state -> compiler free to pipeline.
__global__ __launch_bounds__(256, 1)
void router_df(const float* __restrict__ x,
               const unsigned short* __restrict__ whi,
               const unsigned short* __restrict__ wlo,
               float* __restrict__ out,
               int* __restrict__ flags)
{
    __shared__ float lbuf[4][MT * E];   // per-wave partial logits, 16 KB
    __shared__ float ssbuf[64];
    __shared__ float sfac[16];

    const int t    = threadIdx.x;
    const int wid  = t >> 6;
    const int lane = t & 63;
    const int lsub = lane & 15;         // A-frag row
    const int lgrp = lane >> 4;         // A-frag k-group
    const int row0 = blockIdx.x * MT;

    const float* xbase = x + (size_t)(row0 + lsub) * H + wid * 512 + lgrp * 8;

    f32x4 acc[4] = {{0.f,0.f,0.f,0.f},{0.f,0.f,0.f,0.f},
                    {0.f,0.f,0.f,0.f},{0.f,0.f,0.f,0.f}};
    float sq = 0.0f;

    for (int kl = 0; kl < KCW; ++kl) {
        // x in fragment layout: 8 consecutive k-floats for (row lsub, kgroup lgrp)
        const float4 a0 = *(const float4*)(xbase + kl * 32);
        const float4 a1 = *(const float4*)(xbase + kl * 32 + 4);

        // W' fragments for this kc (4 n-blocks, hi+lo)
        const int kc = wid * KCW + kl;
        const unsigned short* ph = whi + ((size_t)kc * 256 + lane) * 8;
        const unsigned short* pl = wlo + ((size_t)kc * 256 + lane) * 8;
        short8 bh[4], bl[4];
#pragma unroll
        for (int n = 0; n < 4; ++n) {
            bh[n] = *(const short8*)(ph + n * 512);
            bl[n] = *(const short8*)(pl + n * 512);
        }

        sq += a0.x * a0.x + a0.y * a0.y + a0.z * a0.z + a0.w * a0.w
            + a1.x * a1.x + a1.y * a1.y + a1.z * a1.z + a1.w * a1.w;

        // split x -> bf16 hi/lo (pds already folded into W')
        const float xf[8] = { a0.x, a0.y, a0.z, a0.w, a1.x, a1.y, a1.z, a1.w };
        short8 ah, al;
#pragma unroll
        for (int e = 0; e < 8; ++e) {
            const unsigned short hb = bf16_rne(xf[e]);
            const unsigned short lb = bf16_rne(xf[e] - __uint_as_float((unsigned)hb << 16));
            ah[e] = (short)hb;
            al[e] = (short)lb;
        }

#pragma unroll
        for (int n = 0; n < 4; ++n) {
            acc[n] = __builtin_amdgcn_mfma_f32_16x16x32_bf16(ah, bh[n], acc[n], 0, 0, 0);
            acc[n] = __builtin_amdgcn_mfma_f32_16x16x32_bf16(ah, bl[n], acc[n], 0, 0, 0);
            acc[n] = __builtin_amdgcn_mfma_f32_16x16x32_bf16(al, bh[n], acc[n], 0, 0, 0);
        }
    }

    // ---- per-wave partial logits (C frag: col=lane&15, row=(lane>>4)*4+q; m89) ----
#pragma unroll
    for (int n = 0; n < 4; ++n)
#pragma unroll
        for (int q = 0; q < 4; ++q)
            lbuf[wid][(lgrp * 4 + q) * E + n * 16 + lsub] = acc[n][q];

    // ---- sum(x^2): reduce the 4 k-group lanes of each row ----
    sq += __shfl_xor(sq, 16);
    sq += __shfl_xor(sq, 32);
    if (lane < 16) ssbuf[wid * 16 + lane] = sq;
    __syncthreads();

    if (t < 16) {
        const float tot = ssbuf[t] + ssbuf[16 + t] + ssbuf[32 + t] + ssbuf[48 + t];
        sfac[t] = rsqrtf(tot * (1.0f / (float)H) + 1e-6f) * 0.022097086912079608f;
    }
    __syncthreads();

    // ---- epilogue (verified r5-r9): wave wid owns rows wid*4..+3; lane=expert ----
#pragma unroll
    for (int rr = 0; rr < 4; ++rr) {
        const int r = wid * 4 + rr;
        const float L = (lbuf[0][r * E + lane] + lbuf[1][r * E + lane]
                       + lbuf[2][r * E + lane] + lbuf[3][r * E + lane]) * sfac[r];

        float m = L;
#pragma unroll
        for (int off = 32; off >= 1; off >>= 1)
            m = fmaxf(m, __shfl_xor(m, off));
        const float ev = expf(L - m);
        float S = ev;
#pragma unroll
        for (int off = 32; off >= 1; off >>= 1)
            S += __shfl_xor(S, off);
        const float p = ev / S;

        float v1 = p; int i1 = lane;
#pragma unroll
        for (int off = 32; off >= 1; off >>= 1) {
            const float ov = __shfl_xor(v1, off);
            const int   oi = __shfl_xor(i1, off);
            if (ov > v1 || (ov == v1 && oi < i1)) { v1 = ov; i1 = oi; }
        }
        float v2 = (lane == i1) ? -1.0f : p; int i2 = lane;
#pragma unroll
        for (int off = 32; off >= 1; off >>= 1) {
            const float ov = __shfl_xor(v2, off);
            const int   oi = __shfl_xor(i2, off);
            if (ov > v2 || (ov == v2 && oi < i2)) { v2 = ov; i2 = oi; }
        }
        float v3 = (lane == i1 || lane == i2) ? -1.0f : p;
#pragma unroll
        for (int off = 32; off >= 1; off >>= 1)
            v3 = fmaxf(v3, __shfl_xor(v3, off));

        if (lane == 0 && (v2 - v3) < TAU) {
            const int k = atomicAdd(flags, 1);
            flags[1 + k] = row0 + r;
        }

        const float denom = fmaxf(v1 + v2, 1e-9f);
        const float wA = v1 / denom;
        const float wB = v2 / denom;
        const float o  = (lane == i1) ? wA : ((lane == i2) ? wB : 0.0f);
        out[(size_t)(row0 + r) * E + lane] = o;
    }
}

// ============ kernel F: exact-f64 repair of flagged rows (round-3 proven) ============
__global__ __launch_bounds__(256)
void router_fix(const float* __restrict__ x,
                const float* __restrict__ pds,
                const float* __restrict__ Wm,
                float* __restrict__ out,
                const int* __restrict__ flags)
{
    __shared__ double yd[H];
    __shared__ double parts[4 * E];
    __shared__ double ss[256];

    const int t = threadIdx.x;
    const int count = flags[0];

    for (int j = blockIdx.x; j < count; j += gridDim.x) {
        const int r = flags[1 + j];
        const float* xr = x + (size_t)r * H;

        double s = 0.0;
#pragma unroll
        for (int i = 0; i < 8; ++i) {
            const int h = t * 8 + i;
            const double xv = (double)xr[h];
            s += xv * xv;
            yd[h] = xv * (double)pds[h];
        }
        ss[t] = s;
        __syncthreads();

        const int ex = t & 63;
        const int sl = t >> 6;
        const float* wp = Wm + (size_t)(sl * 512) * E + ex;
        double acc = 0.0;
#pragma unroll 8
        for (int h = 0; h < 512; ++h)
            acc = fma(yd[sl * 512 + h], (double)wp[(size_t)h * E], acc);
        parts[sl * E + ex] = acc;
        __syncthreads();

        if (t < 64) {
            const int lane = t;
            double tot = ss[lane * 4] + ss[lane * 4 + 1] + ss[lane * 4 + 2] + ss[lane * 4 + 3];
#pragma unroll
            for (int off = 32; off >= 1; off >>= 1)
                tot += __shfl_xor(tot, off);
            const double sf = (1.0 / sqrt(tot * (1.0 / (double)H) + 1e-6)) * 0.022097086912079608;

            const double Ld = parts[0 * E + lane] + parts[1 * E + lane]
                            + parts[2 * E + lane] + parts[3 * E + lane];
            const float L = (float)(Ld * sf);

            float m = L;
#pragma unroll
            for (int off = 32; off >= 1; off >>= 1)
                m = fmaxf(m, __shfl_xor(m, off));
            const float ev = (float)exp((double)(L - m));
            float S = ev;
#pragma unroll
            for (int off = 32; off >= 1; off >>= 1)
                S += __shfl_xor(S, off);
            const float p = ev / S;

            float v1 = p; int i1 = lane;
#pragma unroll
            for (int off = 32; off >= 1; off >>= 1) {
                const float ov = __shfl_xor(v1, off);
                const int   oi = __shfl_xor(i1, off);
                if (ov > v1 || (ov == v1 && oi < i1)) { v1 = ov; i1 = oi; }
            }
            float v2 = (lane == i1) ? -1.0f : p; int i2 = lane;
#pragma unroll
            for (int off = 32; off >= 1; off >>= 1) {
                const float ov = __shfl_xor(v2, off);
                const int   oi = __shfl_xor(i2, off);
                if (ov > v2 || (ov == v2 && oi < i2)) { v2 = ov; i2 = oi; }
            }

            const float denom = fmaxf(v1 + v2, 1e-9f);
            const float wA = v1 / denom;
            const float wB = v2 / denom;
            const float o  = (lane == i1) ? wA : ((lane == i2) ? wB : 0.0f);
            out[(size_t)r * E + lane] = o;
        }
        __syncthreads();
    }
}

// ============ round-5 fallback (verified) in case ws_size is small ============
__global__ void zero_cnt(int* __restrict__ flags) {
    if (threadIdx.x == 0 && blockIdx.x == 0) flags[0] = 0;
}

__global__ __launch_bounds__(256)
void router_f32(const float* __restrict__ x,
                const float* __restrict__ pds,
                const float* __restrict__ Wm,
                float* __restrict__ out,
                int* __restrict__ flags)
{
    __shared__ __align__(16) float yb[RB * PITCH];
    __shared__ float ssbuf[256];
    __shared__ float sfac[RB];

    const int t    = threadIdx.x;
    const int wv_i = t >> 6;
    const int lane = t & 63;
    const int g    = lane >> 4;
    const int e0   = (lane & 15) << 2;

    const int row0 = blockIdx.x * RB;
    const int srow = t >> 4;
    const int sseg = t & 15;

    const float* xrow = x + (size_t)(row0 + srow) * H;

    float acc[4][4];
#pragma unroll
    for (int a = 0; a < 4; ++a)
#pragma unroll
        for (int b = 0; b < 4; ++b) acc[a][b] = 0.0f;

    float sumsq = 0.0f;
    float4 xv[8];
#pragma unroll
    for (int i = 0; i < 8; ++i)
        xv[i] = *(const float4*)(xrow + sseg * 4 + i * 64);

    for (int c = 0; c < NCH; ++c) {
        const float* pbase = pds + c * CB;
#pragma unroll
        for (int i = 0; i < 8; ++i) {
            const int hl = sseg * 4 + i * 64;
            const float4 a4 = xv[i];
            const float4 p4 = *(const float4*)(pbase + hl);
            sumsq += a4.x * a4.x + a4.y * a4.y + a4.z * a4.z + a4.w * a4.w;
            float4 y4;
            y4.x = a4.x * p4.x; y4.y = a4.y * p4.y;
            y4.z = a4.z * p4.z; y4.w = a4.w * p4.w;
            *(float4*)(&yb[srow * PITCH + hl]) = y4;
        }
        __syncthreads();

        if (c + 1 < NCH) {
            const int h0n = (c + 1) * CB;
#pragma unroll
            for (int i = 0; i < 8; ++i)
                xv[i] = *(const float4*)(xrow + h0n + sseg * 4 + i * 64);
        }

        const int hb = wv_i * 128;
        const float* wbase = Wm + (size_t)(c * CB) * E + e0;
#pragma unroll 2
        for (int s = 0; s < 32; ++s) {
            const int hh = hb + s * 4;
            const float4 w0 = *(const float4*)(wbase + (size_t)(hh + 0) * E);
            const float4 w1 = *(const float4*)(wbase + (size_t)(hh + 1) * E);
            const float4 w2 = *(const float4*)(wbase + (size_t)(hh + 2) * E);
            const float4 w3 = *(const float4*)(wbase + (size_t)(hh + 3) * E);
#pragma unroll
            for (int rr = 0; rr < 4; ++rr) {
                const float4 y4 = *(const float4*)(&yb[(4 * rr + g) * PITCH + hh]);
                acc[rr][0] = fmaf(y4.w, w3.x, fmaf(y4.z, w2.x, fmaf(y4.y, w1.x, fmaf(y4.x, w0.x, acc[rr][0]))));
                acc[rr][1] = fmaf(y4.w, w3.y, fmaf(y4.z, w2.y, fmaf(y4.y, w1.y, fmaf(y4.x, w0.y, acc[rr][1]))));
                acc[rr][2] = fmaf(y4.w, w3.z, fmaf(y4.z, w2.z, fmaf(y4.y, w1.z, fmaf(y4.x, w0.z, acc[rr][2]))));
                acc[rr][3] = fmaf(y4.w, w3.w, fmaf(y4.z, w2.w, fmaf(y4.y, w1.w, fmaf(y4.x, w0.w, acc[rr][3]))));
            }
        }
        __syncthreads();
    }

    ssbuf[t] = sumsq;
    __syncthreads();
    if (t < RB) {
        float tot = 0.0f;
#pragma unroll
        for (int i = 0; i < 16; ++i) tot += ssbuf[t * 16 + i];
        sfac[t] = rsqrtf(tot * (1.0f / (float)H) + 1e-6f) * 0.022097086912079608f;
    }

#pragma unroll
    for (int rr = 0; rr < 4; ++rr) {
        const int r = 4 * rr + g;
        *(float4*)(&yb[((wv_i * RB) + r) * E + e0]) =
            make_float4(acc[rr][0], acc[rr][1], acc[rr][2], acc[rr][3]);
    }
    __syncthreads();

#pragma unroll
    for (int rr = 0; rr < 4; ++rr) {
        const int r = wv_i * 4 + rr;
        float L = yb[(0 * RB + r) * E + lane] + yb[(1 * RB + r) * E + lane]
                + yb[(2 * RB + r) * E + lane] + yb[(3 * RB + r) * E + lane];
        L *= sfac[r];

        float m = L;
#pragma unroll
        for (int off = 32; off >= 1; off >>= 1)
            m = fmaxf(m, __shfl_xor(m, off));
        const float ev = expf(L - m);
        float S = ev;
#pragma unroll
        for (int off = 32; off >= 1; off >>= 1)
            S += __shfl_xor(S, off);
        const float p = ev / S;

        float v1 = p; int i1 = lane;
#pragma unroll
        for (int off = 32; off >= 1; off >>= 1) {
            const float ov = __shfl_xor(v1, off);
            const int   oi = __shfl_xor(i1, off);
            if (ov > v1 || (ov == v1 && oi < i1)) { v1 = ov; i1 = oi; }
        }
        float v2 = (lane == i1) ? -1.0f : p; int i2 = lane;
#pragma unroll
        for (int off = 32; off >= 1; off >>= 1) {
            const float ov = __shfl_xor(v2, off);
            const int   oi = __shfl_xor(i2, off);
            if (ov > v2 || (ov == v2 && oi < i2)) { v2 = ov; i2 = oi; }
        }
        float v3 = (lane == i1 || lane == i2) ? -1.0f : p;
#pragma unroll
        for (int off = 32; off >= 1; off >>= 1)
            v3 = fmaxf(v3, __shfl_xor(v3, off));

        if (lane == 0 && (v2 - v3) < TAU) {
            const int k = atomicAdd(flags, 1);
            flags[1 + k] = row0 + r;
        }

        const float denom = fmaxf(v1 + v2, 1e-9f);
        const float wA = v1 / denom;
        const float wB = v2 / denom;
        const float o  = (lane == i1) ? wA : ((lane == i2) ? wB : 0.0f);
        out[(size_t)(row0 + r) * E + lane] = o;
    }
}

extern "C" void kernel_launch(void* const* d_in, const int* in_sizes, int n_in,
                              void* d_out, int out_size, void* d_ws, size_t ws_size,
                              hipStream_t stream) {
    const float* x   = (const float*)d_in[0];
    const float* pds = (const float*)d_in[1];
    const float* Wm  = (const float*)d_in[2];
    float* out = (float*)d_out;
    int* flags = (int*)d_ws;

    const int T = in_sizes[0] / H;   // 16384

    if (ws_size >= WS_NEEDED) {
        unsigned short* whi = (unsigned short*)((char*)d_ws + WHI_OFF);
        unsigned short* wlo = (unsigned short*)((char*)d_ws + WLO_OFF);
        hipLaunchKernelGGL(prep_w,     dim3(256),    dim3(64),  0, stream, Wm, pds, flags, whi, wlo);
        hipLaunchKernelGGL(router_df,  dim3(T / MT), dim3(256), 0, stream, x, whi, wlo, out, flags);
        hipLaunchKernelGGL(router_fix, dim3(128),    dim3(256), 0, stream, x, pds, Wm, out, flags);
    } else {
        hipLaunchKernelGGL(zero_cnt,   dim3(1),      dim3(64),  0, stream, flags);
        hipLaunchKernelGGL(router_f32, dim3(T / RB), dim3(256), 0, stream, x, pds, Wm, out, flags);
        hipLaunchKernelGGL(router_fix, dim3(128),    dim3(256), 0, stream, x, pds, Wm, out, flags);
    }
}